// Round 2
// baseline (347.224 us; speedup 1.0000x reference)
//
#include <hip/hip_runtime.h>
#include <hip/hip_bf16.h>

typedef __bf16 bf16x8 __attribute__((ext_vector_type(8)));
typedef __bf16 bf16x4 __attribute__((ext_vector_type(4)));
typedef float  f32x4  __attribute__((ext_vector_type(4)));

#define MFMA_BF16(a, b, c) __builtin_amdgcn_mfma_f32_16x16x32_bf16((a), (b), (c), 0, 0, 0)

#define GLOAD_LDS16(g, l)                                          \
  __builtin_amdgcn_global_load_lds(                                \
      (const __attribute__((address_space(1))) void*)(g),          \
      (__attribute__((address_space(3))) void*)(l), 16, 0, 0)

static constexpr int kDim = 1024;
static constexpr int kHeads = 16;
static constexpr int kHD = 64;
static constexpr int kB = 4;
static constexpr int kNQ = 1024;
static constexpr int kNKV = 1024;

// ---------------------------------------------------------------------------
// Dtype hedge: inputs are fp32 per the reference, but the dataset may have
// converted to bf16. Probe Wq as bf16: true-bf16 => max ~0.3; fp32-misread =>
// low mantissa halves decode to huge/NaN bf16 patterns. flag=1 <=> fp32.
// ---------------------------------------------------------------------------
__global__ void detect_dtype(const __bf16* __restrict__ probe, int* __restrict__ flag) {
  __shared__ int any;
  if (threadIdx.x == 0) any = 0;
  __syncthreads();
  float m = 0.f;
  for (int i = threadIdx.x; i < 4096; i += 256) {
    const float v = (float)probe[i];
    const float a = fabsf(v);
    if (a > 1e4f || a != a) m = 1.f;  // huge or NaN pattern => fp32 bytes
  }
  if (m > 0.f) atomicOr(&any, 1);
  __syncthreads();
  if (threadIdx.x == 0) *flag = any;
}

struct ConvArgs {
  const void* src[11];
  __bf16* dst[11];
  int n[11];
};

// Canonicalize all inputs to bf16 in ws. blockIdx.y selects the buffer.
__global__ __launch_bounds__(256) void convert_all(ConvArgs a, const int* __restrict__ flag) {
  const int which = blockIdx.y;
  const int n4 = a.n[which] >> 2;
  const bool f32in = (*flag != 0);
  __bf16* __restrict__ dst = a.dst[which];
  const int stride = gridDim.x * blockDim.x;
  if (f32in) {
    const float4* __restrict__ s = (const float4*)a.src[which];
    for (int i = blockIdx.x * blockDim.x + threadIdx.x; i < n4; i += stride) {
      const float4 v = s[i];
      bf16x4 o = {(__bf16)v.x, (__bf16)v.y, (__bf16)v.z, (__bf16)v.w};
      *(bf16x4*)(dst + (size_t)i * 4) = o;
    }
  } else {
    const bf16x4* __restrict__ s = (const bf16x4*)a.src[which];
    for (int i = blockIdx.x * blockDim.x + threadIdx.x; i < n4; i += stride)
      *(bf16x4*)(dst + (size_t)i * 4) = s[i];
  }
}

// ---------------------------------------------------------------------------
// C = A(MxK) @ W^T (W is NxK row-major, NT GEMM) + bias; bf16 in, fp32 acc.
// MODE 0: out[row*1024 + col] (fp32 or bf16 per flag)   (O-projection)
// MODE 1: q_buf[b][h][n][d]
// MODE 2: k_buf[b][h][n][d] * rel[b][n]
// MODE 3: vT_buf[b][h][d][n] * rel[b][n]   (transposed for NT PV)
// ---------------------------------------------------------------------------
template <int MODE>
__global__ __launch_bounds__(256) void gemm_nt(const __bf16* __restrict__ A,
                                               const __bf16* __restrict__ W,
                                               const __bf16* __restrict__ bias,
                                               const __bf16* __restrict__ rel,
                                               void* __restrict__ outp,
                                               const int* __restrict__ flag) {
  constexpr int K = kDim;
  __shared__ __bf16 As[128 * 32];  // [row][k], unpadded (global_load_lds order)
  __shared__ __bf16 Bs[128 * 32];
  const int tid = threadIdx.x;
  const int wave = tid >> 6, lane = tid & 63;
  const int lr = lane & 15, quad = lane >> 4;
  const int wm = (wave & 1) << 6, wn = (wave >> 1) << 6;  // 2x2 waves, 64x64 each
  const int m0 = blockIdx.y << 7, n0 = blockIdx.x << 7;

  bool f32out = false;
  if constexpr (MODE == 0) f32out = (*flag != 0);

  f32x4 acc[4][4] = {};

  for (int k0 = 0; k0 < K; k0 += 32) {
    __syncthreads();  // prior iter's ds_reads done before restaging
#pragma unroll
    for (int i = 0; i < 2; ++i) {
      const int ch = tid + (i << 8);  // 512 chunks of 16B per tile
      const int row = ch >> 2, col = (ch & 3) << 3;
      GLOAD_LDS16(A + (size_t)(m0 + row) * K + k0 + col, As + ch * 8);
      GLOAD_LDS16(W + (size_t)(n0 + row) * K + k0 + col, Bs + ch * 8);
    }
    __syncthreads();  // drains vmcnt(0) before s_barrier
    bf16x8 afr[4], bfr[4];
#pragma unroll
    for (int mi = 0; mi < 4; ++mi)
      afr[mi] = *(const bf16x8*)&As[(wm + mi * 16 + lr) * 32 + quad * 8];
#pragma unroll
    for (int ni = 0; ni < 4; ++ni)
      bfr[ni] = *(const bf16x8*)&Bs[(wn + ni * 16 + lr) * 32 + quad * 8];
#pragma unroll
    for (int mi = 0; mi < 4; ++mi)
#pragma unroll
      for (int ni = 0; ni < 4; ++ni)
        acc[mi][ni] = MFMA_BF16(afr[mi], bfr[ni], acc[mi][ni]);
  }

  // D layout: row=(lane>>4)*4+r, col=lane&15 (verified m89/m91)
#pragma unroll
  for (int mi = 0; mi < 4; ++mi)
#pragma unroll
    for (int ni = 0; ni < 4; ++ni) {
      const int col = n0 + wn + ni * 16 + lr;
      const float bc = (float)bias[col];
      const f32x4 v = acc[mi][ni];
#pragma unroll
      for (int r = 0; r < 4; ++r) {
        const int row = m0 + wm + mi * 16 + (quad << 2) + r;
        const float val = v[r] + bc;
        if constexpr (MODE == 0) {
          if (f32out)
            ((float*)outp)[(size_t)row * kDim + col] = val;
          else
            ((__bf16*)outp)[(size_t)row * kDim + col] = (__bf16)val;
        } else {
          __bf16* out = (__bf16*)outp;
          const int bb = row >> 10, nn = row & 1023;
          const int hh = col >> 6, dd = col & 63;
          if constexpr (MODE == 1) {
            out[(((size_t)(bb * kHeads + hh) << 10) + nn) * kHD + dd] = (__bf16)val;
          } else if constexpr (MODE == 2) {
            const float rv = (float)rel[(bb << 10) + nn];
            out[(((size_t)(bb * kHeads + hh) << 10) + nn) * kHD + dd] = (__bf16)(val * rv);
          } else {
            const float rv = (float)rel[(bb << 10) + nn];
            out[(((size_t)(bb * kHeads + hh) << 6) + dd) * (size_t)kNKV + nn] =
                (__bf16)(val * rv);
          }
        }
      }
    }
}

// ---------------------------------------------------------------------------
// One workgroup = one (b, h, 16-row q-block). Full softmax over NKV=1024 in LDS.
// S phys layout: S[m][k] at m*1024 + ((k/8 ^ (m&3))*8) + k%8 (XOR swizzle: the
// PV A-fragment reads (16 lanes = 16 rows, same k-chunk) become 4-way not 16-way).
// ---------------------------------------------------------------------------
__global__ __launch_bounds__(256) void attn16(const __bf16* __restrict__ Qb,
                                              const __bf16* __restrict__ Kb,
                                              const __bf16* __restrict__ Vb,
                                              const __bf16* __restrict__ rel,
                                              __bf16* __restrict__ AO) {
  __shared__ float S[16 * 1024];  // 64 KB
  const int tid = threadIdx.x;
  const int wave = tid >> 6, lane = tid & 63;
  const int lr = lane & 15, quad = lane >> 4;
  const int bid = blockIdx.x;
  const int b = bid >> 10, rem = bid & 1023;
  const int h = rem >> 6, q0 = (rem & 63) << 4;
  const __bf16* Qh = Qb + ((size_t)(b * kHeads + h) << 16);  // [n][64]
  const __bf16* Kh = Kb + ((size_t)(b * kHeads + h) << 16);  // [n][64], has r
  const __bf16* Vh = Vb + ((size_t)(b * kHeads + h) << 16);  // [64][n], has r
  const __bf16* rb = rel + (b << 10);

  // A-fragment of Q: A[m=lane&15][k=quad*8+j], two k-steps of 32
  const __bf16* qrow = Qh + (q0 + lr) * kHD + quad * 8;
  const bf16x8 aq0 = *(const bf16x8*)(qrow);
  const bf16x8 aq1 = *(const bf16x8*)(qrow + 32);

  // Phase 1: S = Q K'^T * scale + log(clip(r,1e-6)); wave w does n-tiles 4i+w
  for (int i = 0; i < 16; ++i) {
    const int n0 = ((i << 2) + wave) << 4;
    const __bf16* krow = Kh + (n0 + lr) * kHD + quad * 8;
    const bf16x8 b0 = *(const bf16x8*)(krow);
    const bf16x8 b1 = *(const bf16x8*)(krow + 32);
    f32x4 acc = {0.f, 0.f, 0.f, 0.f};
    acc = MFMA_BF16(aq0, b0, acc);
    acc = MFMA_BF16(aq1, b1, acc);
    const int kc = n0 + lr;  // D col = lane&15
    const float lg = __logf(fmaxf((float)rb[kc], 1e-6f));
    const int kb = kc >> 3, k7 = kc & 7;
#pragma unroll
    for (int r = 0; r < 4; ++r) {
      const int m = (quad << 2) + r;  // D row = quad*4 + r
      S[(m << 10) + ((kb ^ (m & 3)) << 3) + k7] = acc[r] * 0.125f + lg;
    }
  }
  __syncthreads();

  // Phase 2: row softmax; 16 threads/row, shfl_xor reductions, normalize in place
  {
    const int row = tid >> 4, j0 = tid & 15;
    const int ra = row << 10, rx = row & 3;
    float mx = -1e30f;
    for (int t = 0; t < 64; ++t) {
      const int k = j0 + (t << 4);
      mx = fmaxf(mx, S[ra + (((k >> 3) ^ rx) << 3) + (k & 7)]);
    }
#pragma unroll
    for (int off = 1; off < 16; off <<= 1) mx = fmaxf(mx, __shfl_xor(mx, off, 64));
    float sm = 0.f;
    for (int t = 0; t < 64; ++t) {
      const int k = j0 + (t << 4);
      const int idx = ra + (((k >> 3) ^ rx) << 3) + (k & 7);
      const float p = __expf(S[idx] - mx);
      S[idx] = p;
      sm += p;
    }
#pragma unroll
    for (int off = 1; off < 16; off <<= 1) sm += __shfl_xor(sm, off, 64);
    const float inv = 1.f / sm;
    for (int t = 0; t < 64; ++t) {
      const int k = j0 + (t << 4);
      S[ra + (((k >> 3) ^ rx) << 3) + (k & 7)] *= inv;
    }
  }
  __syncthreads();

  // Phase 3: O = P @ V'^T (V' stored [d][n]); wave w owns d-tile w; 32 k-steps
  {
    const int d0 = wave << 4;
    const __bf16* vrow = Vh + (size_t)(d0 + lr) * kNKV;
    f32x4 acc = {0.f, 0.f, 0.f, 0.f};
    const int sb = lr << 10, rx = lr & 3;
    for (int kk = 0; kk < 32; ++kk) {
      const int kb = (kk << 2) + quad;  // A-frag k-chunk (8 wide)
      const int off = sb + ((kb ^ rx) << 3);
      const f32x4 p0 = *(const f32x4*)&S[off];
      const f32x4 p1 = *(const f32x4*)&S[off + 4];
      bf16x8 af;
#pragma unroll
      for (int j = 0; j < 4; ++j) {
        af[j] = (__bf16)p0[j];
        af[j + 4] = (__bf16)p1[j];
      }
      const bf16x8 bv = *(const bf16x8*)(vrow + (kk << 5) + (quad << 3));
      acc = MFMA_BF16(af, bv, acc);
    }
    const int dcol = (h << 6) + d0 + lr;
    const size_t ob = ((size_t)(b << 10) + q0);
#pragma unroll
    for (int r = 0; r < 4; ++r)
      AO[(ob + (quad << 2) + r) * kDim + dcol] = (__bf16)acc[r];
  }
}

extern "C" void kernel_launch(void* const* d_in, const int* in_sizes, int n_in,
                              void* d_out, int out_size, void* d_ws, size_t ws_size,
                              hipStream_t stream) {
  (void)in_sizes; (void)n_in; (void)out_size; (void)ws_size;

  char* base = (char*)d_ws;
  int* flag = (int*)base;
  __bf16* p = (__bf16*)(base + 256);
  const size_t big = (size_t)kB * kNQ * kDim;  // 4M elements

  __bf16* cqf  = p; p += big;
  __bf16* ckvf = p; p += big;
  __bf16* crel = p; p += kB * kNKV;
  __bf16* cWq  = p; p += kDim * kDim;
  __bf16* cbq  = p; p += kDim;
  __bf16* cWk  = p; p += kDim * kDim;
  __bf16* cbk  = p; p += kDim;
  __bf16* cWv  = p; p += kDim * kDim;
  __bf16* cbv  = p; p += kDim;
  __bf16* cWo  = p; p += kDim * kDim;
  __bf16* cbo  = p; p += kDim;
  __bf16* q_buf  = p; p += big;
  __bf16* k_buf  = p; p += big;
  __bf16* vT_buf = p; p += big;
  __bf16* ao_buf = p; p += big;

  detect_dtype<<<1, 256, 0, stream>>>((const __bf16*)d_in[3], flag);

  ConvArgs ca;
  __bf16* dsts[11] = {cqf, ckvf, crel, cWq, cbq, cWk, cbk, cWv, cbv, cWo, cbo};
  const int ns[11] = {(int)big, (int)big, kB * kNKV,
                      kDim * kDim, kDim, kDim * kDim, kDim,
                      kDim * kDim, kDim, kDim * kDim, kDim};
  for (int i = 0; i < 11; ++i) { ca.src[i] = d_in[i]; ca.dst[i] = dsts[i]; ca.n[i] = ns[i]; }
  convert_all<<<dim3(256, 11), 256, 0, stream>>>(ca, flag);

  const dim3 grid(kDim / 128, (kB * kNQ) / 128);  // (8, 32)
  gemm_nt<1><<<grid, 256, 0, stream>>>(cqf,  cWq, cbq, crel, q_buf,  flag);
  gemm_nt<2><<<grid, 256, 0, stream>>>(ckvf, cWk, cbk, crel, k_buf,  flag);
  gemm_nt<3><<<grid, 256, 0, stream>>>(ckvf, cWv, cbv, crel, vT_buf, flag);
  attn16<<<kB * kHeads * (kNQ / 16), 256, 0, stream>>>(q_buf, k_buf, vT_buf, crel, ao_buf);
  gemm_nt<0><<<grid, 256, 0, stream>>>(ao_buf, cWo, cbo, crel, d_out, flag);
}

// Round 3
// 250.635 us; speedup vs baseline: 1.3854x; 1.3854x over previous
//
#include <hip/hip_runtime.h>
#include <hip/hip_bf16.h>

typedef __bf16 bf16x8 __attribute__((ext_vector_type(8)));
typedef __bf16 bf16x4 __attribute__((ext_vector_type(4)));
typedef float  f32x4  __attribute__((ext_vector_type(4)));

#define MFMA_BF16(a, b, c) __builtin_amdgcn_mfma_f32_16x16x32_bf16((a), (b), (c), 0, 0, 0)

#define GLOAD_LDS16(g, l)                                          \
  __builtin_amdgcn_global_load_lds(                                \
      (const __attribute__((address_space(1))) void*)(g),          \
      (__attribute__((address_space(3))) void*)(l), 16, 0, 0)

static constexpr int kDim = 1024;
static constexpr int kHeads = 16;
static constexpr int kB = 4;
static constexpr int kNQ = 1024;
static constexpr int kNKV = 1024;

// ---------------------------------------------------------------------------
// fp32 -> bf16 canonicalization (inputs confirmed fp32: round-1 NaN under
// bf16-read, round-2 pass with fp32 path). blockIdx.y selects buffer.
// ---------------------------------------------------------------------------
struct Conv6 {
  const float* src[6];
  __bf16* dst[6];
  int n4[6];
};
__global__ __launch_bounds__(256) void convert6(Conv6 a) {
  const int w = blockIdx.y;
  const float4* __restrict__ s = (const float4*)a.src[w];
  __bf16* __restrict__ d = a.dst[w];
  const int n4 = a.n4[w];
  const int stride = gridDim.x * blockDim.x;
  for (int i = blockIdx.x * blockDim.x + threadIdx.x; i < n4; i += stride) {
    const float4 v = s[i];
    bf16x4 o = {(__bf16)v.x, (__bf16)v.y, (__bf16)v.z, (__bf16)v.w};
    *(bf16x4*)(d + (size_t)i * 4) = o;
  }
}

// ---------------------------------------------------------------------------
// Shared NT-GEMM core: C = A(MxK=1024) @ W^T + bias (fp32), bf16 MFMA.
// mode 1: q_buf[b][h][n][d]
// mode 2: k_buf[b][h][n][d] * rel[b][n]
// mode 3: vT_buf[b][h][d][n] * rel[b][n]   (transposed for NT PV)
// ---------------------------------------------------------------------------
struct QKVArgs {
  const __bf16* A[3];
  const __bf16* W[3];
  const float* bias[3];
  const float* rel;
  __bf16* out[3];
};

__global__ __launch_bounds__(256) void qkv_gemm(QKVArgs args) {
  constexpr int K = kDim;
  __shared__ __bf16 As[128 * 32];
  __shared__ __bf16 Bs[128 * 32];
  const int z = blockIdx.z;  // 0=Q, 1=K, 2=V
  const __bf16* __restrict__ A = args.A[z];
  const __bf16* __restrict__ W = args.W[z];
  const float* __restrict__ bias = args.bias[z];
  const float* __restrict__ rel = args.rel;
  __bf16* __restrict__ out = args.out[z];

  const int tid = threadIdx.x;
  const int wave = tid >> 6, lane = tid & 63;
  const int lr = lane & 15, quad = lane >> 4;
  const int wm = (wave & 1) << 6, wn = (wave >> 1) << 6;
  const int m0 = blockIdx.y << 7, n0 = blockIdx.x << 7;

  f32x4 acc[4][4] = {};

  for (int k0 = 0; k0 < K; k0 += 32) {
    __syncthreads();
#pragma unroll
    for (int i = 0; i < 2; ++i) {
      const int ch = tid + (i << 8);
      const int row = ch >> 2, col = (ch & 3) << 3;
      GLOAD_LDS16(A + (size_t)(m0 + row) * K + k0 + col, As + ch * 8);
      GLOAD_LDS16(W + (size_t)(n0 + row) * K + k0 + col, Bs + ch * 8);
    }
    __syncthreads();
    bf16x8 afr[4], bfr[4];
#pragma unroll
    for (int mi = 0; mi < 4; ++mi)
      afr[mi] = *(const bf16x8*)&As[(wm + mi * 16 + lr) * 32 + quad * 8];
#pragma unroll
    for (int ni = 0; ni < 4; ++ni)
      bfr[ni] = *(const bf16x8*)&Bs[(wn + ni * 16 + lr) * 32 + quad * 8];
#pragma unroll
    for (int mi = 0; mi < 4; ++mi)
#pragma unroll
      for (int ni = 0; ni < 4; ++ni)
        acc[mi][ni] = MFMA_BF16(afr[mi], bfr[ni], acc[mi][ni]);
  }

  // D layout: row=(lane>>4)*4+r, col=lane&15 (verified)
#pragma unroll
  for (int mi = 0; mi < 4; ++mi)
#pragma unroll
    for (int ni = 0; ni < 4; ++ni) {
      const int col = n0 + wn + ni * 16 + lr;
      const float bc = bias[col];
      const f32x4 v = acc[mi][ni];
#pragma unroll
      for (int r = 0; r < 4; ++r) {
        const int row = m0 + wm + mi * 16 + (quad << 2) + r;
        const float val = v[r] + bc;
        const int bb = row >> 10, nn = row & 1023;
        const int hh = col >> 6, dd = col & 63;
        if (z == 0) {
          out[(((size_t)(bb * kHeads + hh) << 10) + nn) * 64 + dd] = (__bf16)val;
        } else if (z == 1) {
          const float rv = rel[(bb << 10) + nn];
          out[(((size_t)(bb * kHeads + hh) << 10) + nn) * 64 + dd] = (__bf16)(val * rv);
        } else {
          const float rv = rel[(bb << 10) + nn];
          out[(((size_t)(bb * kHeads + hh) << 6) + dd) * (size_t)kNKV + nn] =
              (__bf16)(val * rv);
        }
      }
    }
}

// O-projection: fp32 output straight to d_out.
__global__ __launch_bounds__(256) void o_gemm(const __bf16* __restrict__ A,
                                              const __bf16* __restrict__ W,
                                              const float* __restrict__ bias,
                                              float* __restrict__ out) {
  constexpr int K = kDim;
  __shared__ __bf16 As[128 * 32];
  __shared__ __bf16 Bs[128 * 32];
  const int tid = threadIdx.x;
  const int wave = tid >> 6, lane = tid & 63;
  const int lr = lane & 15, quad = lane >> 4;
  const int wm = (wave & 1) << 6, wn = (wave >> 1) << 6;
  const int m0 = blockIdx.y << 7, n0 = blockIdx.x << 7;

  f32x4 acc[4][4] = {};
  for (int k0 = 0; k0 < K; k0 += 32) {
    __syncthreads();
#pragma unroll
    for (int i = 0; i < 2; ++i) {
      const int ch = tid + (i << 8);
      const int row = ch >> 2, col = (ch & 3) << 3;
      GLOAD_LDS16(A + (size_t)(m0 + row) * K + k0 + col, As + ch * 8);
      GLOAD_LDS16(W + (size_t)(n0 + row) * K + k0 + col, Bs + ch * 8);
    }
    __syncthreads();
    bf16x8 afr[4], bfr[4];
#pragma unroll
    for (int mi = 0; mi < 4; ++mi)
      afr[mi] = *(const bf16x8*)&As[(wm + mi * 16 + lr) * 32 + quad * 8];
#pragma unroll
    for (int ni = 0; ni < 4; ++ni)
      bfr[ni] = *(const bf16x8*)&Bs[(wn + ni * 16 + lr) * 32 + quad * 8];
#pragma unroll
    for (int mi = 0; mi < 4; ++mi)
#pragma unroll
      for (int ni = 0; ni < 4; ++ni)
        acc[mi][ni] = MFMA_BF16(afr[mi], bfr[ni], acc[mi][ni]);
  }
#pragma unroll
  for (int mi = 0; mi < 4; ++mi)
#pragma unroll
    for (int ni = 0; ni < 4; ++ni) {
      const int col = n0 + wn + ni * 16 + lr;
      const float bc = bias[col];
      const f32x4 v = acc[mi][ni];
#pragma unroll
      for (int r = 0; r < 4; ++r) {
        const int row = m0 + wm + mi * 16 + (quad << 2) + r;
        out[(size_t)row * kDim + col] = v[r] + bc;
      }
    }
}

// ---------------------------------------------------------------------------
// Attention: one WG = (b, h, 32 q-rows). S holds P = exp(qk*scale + log r) as
// bf16 (32x1024 = 64 KB), 8-elem-chunk XOR swizzle (chunk ^= row&7):
//   - phase-1 scalar b16 stores ~2-way (free), phase-3 ds_read_b128 conflict-free.
// No max-subtraction: |logits| <= ~12 (|q.k|*0.125 + log r <= 0), exp fp32-safe.
// Row sum l via ones-B-fragment MFMA in the PV loop (lands in epilogue regs).
// ---------------------------------------------------------------------------
__global__ __launch_bounds__(256) void attn32(const __bf16* __restrict__ Qb,
                                              const __bf16* __restrict__ Kb,
                                              const __bf16* __restrict__ Vb,
                                              const float* __restrict__ rel,
                                              __bf16* __restrict__ AO) {
  __shared__ __bf16 S[32 * 1024];  // 64 KB
  const int tid = threadIdx.x;
  const int wave = tid >> 6, lane = tid & 63;
  const int lr = lane & 15, quad = lane >> 4;
  const int bid = blockIdx.x;
  const int b = bid >> 9, rem = bid & 511;
  const int h = rem >> 5, q0 = (rem & 31) << 5;
  const __bf16* Qh = Qb + ((size_t)(b * kHeads + h) << 16);  // [n][64]
  const __bf16* Kh = Kb + ((size_t)(b * kHeads + h) << 16);  // [n][64] (has r)
  const __bf16* Vh = Vb + ((size_t)(b * kHeads + h) << 16);  // [64][n] (has r)
  const float* rb = rel + (b << 10);

  // Q A-fragments for 2 m-tiles: A[m=lane&15][k=quad*8+j]
  bf16x8 aq[2][2];
#pragma unroll
  for (int mt = 0; mt < 2; ++mt) {
    const __bf16* qrow = Qh + (q0 + mt * 16 + lr) * 64 + quad * 8;
    aq[mt][0] = *(const bf16x8*)qrow;
    aq[mt][1] = *(const bf16x8*)(qrow + 32);
  }

  // Phase 1: P = exp(QK'^T * 0.125 + log(clip(r))), stored bf16 swizzled.
  for (int i = 0; i < 16; ++i) {
    const int n0 = (((i << 2) + wave) << 4);
    const __bf16* krow = Kh + (n0 + lr) * 64 + quad * 8;
    const bf16x8 kb0 = *(const bf16x8*)krow;
    const bf16x8 kb1 = *(const bf16x8*)(krow + 32);
    const int col = n0 + lr;  // D col = lane&15
    const float lg = __logf(fmaxf(rb[col], 1e-6f));
    const int cb = col >> 3, c7 = col & 7;
#pragma unroll
    for (int mt = 0; mt < 2; ++mt) {
      f32x4 acc = {0.f, 0.f, 0.f, 0.f};
      acc = MFMA_BF16(aq[mt][0], kb0, acc);
      acc = MFMA_BF16(aq[mt][1], kb1, acc);
#pragma unroll
      for (int r = 0; r < 4; ++r) {
        const int row = mt * 16 + (quad << 2) + r;  // D row = quad*4+r
        const float p = __expf(acc[r] * 0.125f + lg);
        S[(row << 10) + (((cb ^ (row & 7)) << 3) + c7)] = (__bf16)p;
      }
    }
  }
  __syncthreads();

  // Phase 3: O = P V'^T (V' stored [d][n]); wave = d-tile; ones-MFMA gives l.
  bf16x8 ones;
#pragma unroll
  for (int j = 0; j < 8; ++j) ones[j] = (__bf16)1.0f;
  const int d0 = wave << 4;
  const __bf16* vrow = Vh + (size_t)(d0 + lr) * kNKV;
  f32x4 accO[2] = {{0.f, 0.f, 0.f, 0.f}, {0.f, 0.f, 0.f, 0.f}};
  f32x4 accL[2] = {{0.f, 0.f, 0.f, 0.f}, {0.f, 0.f, 0.f, 0.f}};
  const int xr = lr & 7;
  for (int kk = 0; kk < 32; ++kk) {
    const int c = (kk << 2) + quad;  // 8-elem chunk index of A-frag
    const bf16x8 bv = *(const bf16x8*)(vrow + (kk << 5) + (quad << 3));
#pragma unroll
    for (int mt = 0; mt < 2; ++mt) {
      const int row = mt * 16 + lr;  // A-frag m = lane&15
      const bf16x8 af = *(const bf16x8*)&S[(row << 10) + ((c ^ xr) << 3)];
      accO[mt] = MFMA_BF16(af, bv, accO[mt]);
      accL[mt] = MFMA_BF16(af, ones, accL[mt]);
    }
  }
#pragma unroll
  for (int mt = 0; mt < 2; ++mt)
#pragma unroll
    for (int r = 0; r < 4; ++r) {
      const int row = q0 + mt * 16 + (quad << 2) + r;
      AO[((size_t)(b << 10) + row) * kDim + (h << 6) + d0 + lr] =
          (__bf16)(accO[mt][r] / accL[mt][r]);
    }
}

extern "C" void kernel_launch(void* const* d_in, const int* in_sizes, int n_in,
                              void* d_out, int out_size, void* d_ws, size_t ws_size,
                              hipStream_t stream) {
  (void)in_sizes; (void)n_in; (void)out_size; (void)ws_size;
  const float* qf  = (const float*)d_in[0];
  const float* kvf = (const float*)d_in[1];
  const float* rel = (const float*)d_in[2];
  const float* Wq  = (const float*)d_in[3];
  const float* bq  = (const float*)d_in[4];
  const float* Wk  = (const float*)d_in[5];
  const float* bk  = (const float*)d_in[6];
  const float* Wv  = (const float*)d_in[7];
  const float* bv  = (const float*)d_in[8];
  const float* Wo  = (const float*)d_in[9];
  const float* bo  = (const float*)d_in[10];

  const size_t big = (size_t)kB * kNQ * kDim;  // 4M elements
  __bf16* p = (__bf16*)d_ws;
  __bf16* cqf  = p; p += big;
  __bf16* ckvf = p; p += big;
  __bf16* cWq  = p; p += kDim * kDim;
  __bf16* cWk  = p; p += kDim * kDim;
  __bf16* cWv  = p; p += kDim * kDim;
  __bf16* cWo  = p; p += kDim * kDim;
  __bf16* q_buf  = p; p += big;
  __bf16* k_buf  = p; p += big;
  __bf16* vT_buf = p; p += big;
  __bf16* ao_buf = p; p += big;  // total ~56 MB

  Conv6 cv;
  const float* srcs[6] = {qf, kvf, Wq, Wk, Wv, Wo};
  __bf16* dsts[6] = {cqf, ckvf, cWq, cWk, cWv, cWo};
  const int n4s[6] = {(int)(big >> 2), (int)(big >> 2),
                      kDim * kDim / 4, kDim * kDim / 4, kDim * kDim / 4, kDim * kDim / 4};
  for (int i = 0; i < 6; ++i) { cv.src[i] = srcs[i]; cv.dst[i] = dsts[i]; cv.n4[i] = n4s[i]; }
  convert6<<<dim3(256, 6), 256, 0, stream>>>(cv);

  QKVArgs qa;
  qa.A[0] = cqf;  qa.A[1] = ckvf; qa.A[2] = ckvf;
  qa.W[0] = cWq;  qa.W[1] = cWk;  qa.W[2] = cWv;
  qa.bias[0] = bq; qa.bias[1] = bk; qa.bias[2] = bv;
  qa.rel = rel;
  qa.out[0] = q_buf; qa.out[1] = k_buf; qa.out[2] = vT_buf;
  qkv_gemm<<<dim3(kDim / 128, (kB * kNQ) / 128, 3), 256, 0, stream>>>(qa);

  attn32<<<kB * kHeads * (kNQ / 32), 256, 0, stream>>>(q_buf, k_buf, vT_buf, rel, ao_buf);

  o_gemm<<<dim3(kDim / 128, (kB * kNQ) / 128), 256, 0, stream>>>(ao_buf, cWo, bo, (float*)d_out);
}